// Round 11
// baseline (924.212 us; speedup 1.0000x reference)
//
#include <hip/hip_runtime.h>

typedef unsigned short u16;
typedef unsigned int   u32;

using short8  = __attribute__((ext_vector_type(8))) short;
using floatx4 = __attribute__((ext_vector_type(4))) float;

// ---------- constants ----------
#define Bb   16
#define Hh   56
#define Ww   56
#define Cc   512
#define NHh  16
#define HDd  32
#define HIDh 2048
#define Ll   (Hh*Ww)          // 3136
#define Mm   (Bb*Ll)          // 50176
#define SCALE 0.17677669529663687f
#define CSTR 136              // GEMM C-tile LDS row stride (u16)
#define PSTR 72               // attn LDS row stride (u16): 144B = 16B-aligned

// ---------- helpers ----------
__device__ __forceinline__ u16 f2bf(float f) {
  union { float f; u32 u; } v; v.f = f;
  u32 r = (v.u + 0x7fffu + ((v.u >> 16) & 1u)) >> 16;
  return (u16)r;
}
__device__ __forceinline__ float bf2f(u16 u) {
  union { u32 u; float f; } v; v.u = ((u32)u) << 16; return v.f;
}
__device__ __forceinline__ float bf2f_lo(u32 u) {
  union { u32 u; float f; } v; v.u = u << 16; return v.f;
}
__device__ __forceinline__ float bf2f_hi(u32 u) {
  union { u32 u; float f; } v; v.u = u & 0xffff0000u; return v.f;
}
// gelu with A&S 7.1.26 erf (|err| < 1.5e-7): ~2x cheaper than libm erff.
__device__ __forceinline__ float gelu_f(float x) {
  const float z  = x * 0.70710678118654752f;
  const float az = fabsf(z);
  const float t  = __builtin_amdgcn_rcpf(fmaf(0.3275911f, az, 1.f));
  float p = fmaf(1.061405429f, t, -1.453152027f);
  p = fmaf(p, t, 1.421413741f);
  p = fmaf(p, t, -0.284496736f);
  p = fmaf(p, t, 0.254829592f);
  const float e = p * t * __expf(-z * z);     // 1 - erf(|z|)
  float erfz = 1.f - e;
  erfz = copysignf(erfz, z);
  return 0.5f * x * (1.f + erfz);
}
__device__ __forceinline__ void gld_lds16(const u16* g, u16* l) {
  __builtin_amdgcn_global_load_lds(
      (__attribute__((address_space(1))) void*)(void*)g,
      (__attribute__((address_space(3))) void*)(void*)l,
      16, 0, 0);
}

// ---------- fused prep: weight cvt+transpose (row-major Wt[n][k]) +
//            bias concat + rel-bias fragment prep — ONE launch ----------
// block ranges: [0,3072) wQKV | [3072,4096) wWp | [4096,8192) wW1 |
//               [8192,12288) wW2 | [12288,12544) relL | 12544 bcat
__global__ __launch_bounds__(256)
void prep_k(const float* __restrict__ Wq, const float* __restrict__ Wk,
            const float* __restrict__ Wv, const float* __restrict__ Wp,
            const float* __restrict__ W1, const float* __restrict__ W2,
            const float* __restrict__ bq, const float* __restrict__ bk,
            const float* __restrict__ bv, const float* __restrict__ rel,
            u16* __restrict__ wQKV, u16* __restrict__ wWp,
            u16* __restrict__ wW1, u16* __restrict__ wW2,
            float* __restrict__ bqkv, float* __restrict__ relL) {
  const int blk = blockIdx.x;
  if (blk < 3072) {            // wQKV: 3 matrices 512x512, Wt[n][k]=W[k][n]
    int idx = blk * 256 + threadIdx.x;     // 0..786431
    int m = idx >> 18;                     // which of Wq/Wk/Wv
    int r = idx & 262143;
    int n = r >> 9, k = r & 511;
    const float* W = (m == 0) ? Wq : (m == 1) ? Wk : Wv;
    wQKV[idx] = f2bf(W[(size_t)k * 512 + n]);
  } else if (blk < 4096) {     // wWp: 512x512
    int idx = (blk - 3072) * 256 + threadIdx.x;
    int n = idx >> 9, k = idx & 511;
    wWp[idx] = f2bf(Wp[(size_t)k * 512 + n]);
  } else if (blk < 8192) {     // wW1: N=2048, K=512
    int idx = (blk - 4096) * 256 + threadIdx.x;
    int n = idx >> 9, k = idx & 511;
    wW1[idx] = f2bf(W1[(size_t)k * 2048 + n]);
  } else if (blk < 12288) {    // wW2: N=512, K=2048
    int idx = (blk - 8192) * 256 + threadIdx.x;
    int n = idx >> 11, k = idx & 2047;
    wW2[idx] = f2bf(W2[(size_t)k * 512 + n]);
  } else if (blk < 12544) {    // relL: MFMA D-fragment layout, masks baked
    int idx  = (blk - 12288) * 256 + threadIdx.x;   // 0..65535
    int reg  = idx & 3;
    int lane = (idx >> 2) & 63;
    int frag = (idx >> 8) & 15;
    int h    = idx >> 12;
    int mi = frag >> 2, nj = frag & 3;
    int row = mi * 16 + (lane >> 4) * 4 + reg;
    int col = nj * 16 + (lane & 15);
    float v;
    if (col >= 49)      v = -1e30f;
    else if (row >= 49) v = 0.f;
    else                v = rel[((size_t)h * 49 + row) * 49 + col];
    relL[idx] = v;
  } else {                     // bcat: 1536 elems
    for (int i = threadIdx.x; i < 1536; i += 256) {
      float v = (i < 512) ? bq[i] : (i < 1024) ? bk[i - 512] : bv[i - 1024];
      bqkv[i] = v;
    }
  }
}

// ---------- layernorm fp32 in -> bf16 out, one wave per row ----------
__global__ __launch_bounds__(256)
void ln_k(const float* __restrict__ x, const float* __restrict__ g,
          const float* __restrict__ b, u16* __restrict__ out) {
  const int row  = blockIdx.x * 4 + (threadIdx.x >> 6);
  const int lane = threadIdx.x & 63;
  const float* xr = x + (size_t)row * Cc + lane * 8;
  float4 v0 = *(const float4*)xr;
  float4 v1 = *(const float4*)(xr + 4);
  float s  = v0.x+v0.y+v0.z+v0.w + v1.x+v1.y+v1.z+v1.w;
  float s2 = v0.x*v0.x+v0.y*v0.y+v0.z*v0.z+v0.w*v0.w
           + v1.x*v1.x+v1.y*v1.y+v1.z*v1.z+v1.w*v1.w;
  #pragma unroll
  for (int off = 32; off >= 1; off >>= 1) {
    s  += __shfl_xor(s,  off);
    s2 += __shfl_xor(s2, off);
  }
  float mu  = s  * (1.f/512.f);
  float var = s2 * (1.f/512.f) - mu*mu;
  float rs  = rsqrtf(var + 1e-5f);
  float4 ga = *(const float4*)(g + lane*8);
  float4 gb = *(const float4*)(g + lane*8 + 4);
  float4 ba = *(const float4*)(b + lane*8);
  float4 bb = *(const float4*)(b + lane*8 + 4);
  float o0 = (v0.x-mu)*rs*ga.x + ba.x;
  float o1 = (v0.y-mu)*rs*ga.y + ba.y;
  float o2 = (v0.z-mu)*rs*ga.z + ba.z;
  float o3 = (v0.w-mu)*rs*ga.w + ba.w;
  float o4 = (v1.x-mu)*rs*gb.x + bb.x;
  float o5 = (v1.y-mu)*rs*gb.y + bb.y;
  float o6 = (v1.z-mu)*rs*gb.z + bb.z;
  float o7 = (v1.w-mu)*rs*gb.w + bb.w;
  u32 w0 = (u32)f2bf(o0) | ((u32)f2bf(o1) << 16);
  u32 w1 = (u32)f2bf(o2) | ((u32)f2bf(o3) << 16);
  u32 w2 = (u32)f2bf(o4) | ((u32)f2bf(o5) << 16);
  u32 w3 = (u32)f2bf(o6) | ((u32)f2bf(o7) << 16);
  *(uint4*)(out + (size_t)row * Cc + lane * 8) = make_uint4(w0, w1, w2, w3);
}

// ---------- layernorm bf16 in -> bf16 out ----------
__global__ __launch_bounds__(256)
void ln_bf_k(const u16* __restrict__ x, const float* __restrict__ g,
             const float* __restrict__ b, u16* __restrict__ out) {
  const int row  = blockIdx.x * 4 + (threadIdx.x >> 6);
  const int lane = threadIdx.x & 63;
  uint4 xv = *(const uint4*)(x + (size_t)row * Cc + lane * 8);
  float v[8];
  v[0]=bf2f_lo(xv.x); v[1]=bf2f_hi(xv.x); v[2]=bf2f_lo(xv.y); v[3]=bf2f_hi(xv.y);
  v[4]=bf2f_lo(xv.z); v[5]=bf2f_hi(xv.z); v[6]=bf2f_lo(xv.w); v[7]=bf2f_hi(xv.w);
  float s = 0.f, s2 = 0.f;
  #pragma unroll
  for (int i = 0; i < 8; i++) { s += v[i]; s2 += v[i]*v[i]; }
  #pragma unroll
  for (int off = 32; off >= 1; off >>= 1) {
    s  += __shfl_xor(s,  off);
    s2 += __shfl_xor(s2, off);
  }
  float mu  = s  * (1.f/512.f);
  float var = s2 * (1.f/512.f) - mu*mu;
  float rs  = rsqrtf(var + 1e-5f);
  float4 ga = *(const float4*)(g + lane*8);
  float4 gb = *(const float4*)(g + lane*8 + 4);
  float4 ba = *(const float4*)(b + lane*8);
  float4 bb = *(const float4*)(b + lane*8 + 4);
  float o[8];
  o[0]=(v[0]-mu)*rs*ga.x+ba.x; o[1]=(v[1]-mu)*rs*ga.y+ba.y;
  o[2]=(v[2]-mu)*rs*ga.z+ba.z; o[3]=(v[3]-mu)*rs*ga.w+ba.w;
  o[4]=(v[4]-mu)*rs*gb.x+bb.x; o[5]=(v[5]-mu)*rs*gb.y+bb.y;
  o[6]=(v[6]-mu)*rs*gb.z+bb.z; o[7]=(v[7]-mu)*rs*gb.w+bb.w;
  u32 w0 = (u32)f2bf(o[0]) | ((u32)f2bf(o[1]) << 16);
  u32 w1 = (u32)f2bf(o[2]) | ((u32)f2bf(o[3]) << 16);
  u32 w2 = (u32)f2bf(o[4]) | ((u32)f2bf(o[5]) << 16);
  u32 w3 = (u32)f2bf(o[6]) | ((u32)f2bf(o[7]) << 16);
  *(uint4*)(out + (size_t)row * Cc + lane * 8) = make_uint4(w0, w1, w2, w3);
}

// ---------- GEMM: out[M,N] = A[M,K](bf16) @ Bt[N,K](bf16)^T + bias ----------
// 128x128 tile, BK=32, *** 2 WAVES *** (128 threads), each wave owns 64x128
// (A-frags private, B-frags shared) — cuts LDS read amplification 2x -> 1.5x.
// Rationale (round-10 counters): per step a 4-wave block moved 48KB through
// the LDS pipe (16KB staged writes + 32KB frag reads, 2x amp); measured
// 1084 cyc/step x 3 blocks = 136 B/cyc == the ds_read_b128 ceiling (m134).
// LDS pipe saturation is the 25%-MfmaUtil plateau, not barriers/latency.
// 2-wave split: 16KB writes + 24KB reads = 40KB/step (-17%), 32 MFMA/wave.
// TRIPLE-buffered LDS (3 x 16 KB), depth-2 prefetch, counted vmcnt
// (8 loads/stage now): never 0 mid-loop. 3 blocks/CU (6 waves/CU — low
// occupancy by design; LDS-bound not latency-bound).
// MODE 0: -> bf16   MODE 1: gelu -> bf16   MODE 2: +res(fp32) -> bf16
// MODE 3: +res(bf16) -> fp32 (direct stores)
template<int MODE>
__global__ __launch_bounds__(128, 1)
void gemm_bt(const u16* __restrict__ A, const u16* __restrict__ Bt,
             const float* __restrict__ bias, const void* __restrict__ res,
             void* __restrict__ outp, int M, int N, int K, int nbn) {
  (void)M;
  __shared__ __align__(16) u16 smem[24576];   // 49152 B; 3 bufs; aliases C-stage

  const int b   = blockIdx.x;
  const int xcd = b & 7;
  const int s   = b >> 3;
  const int mt  = (s / nbn) * 8 + xcd;
  const int nt  = s - (s / nbn) * nbn;
  const int m0  = mt * 128;
  const int n0  = nt * 128;

  const int tid  = threadIdx.x;        // 0..127
  const int lane = tid & 63;
  const int wave = tid >> 6;           // 0..1
  const int wm   = wave * 64;          // wave's 64 rows; all 128 cols
  const int quad = lane >> 4;
  const int l16  = lane & 15;

  floatx4 acc[4][8];
  #pragma unroll
  for (int i = 0; i < 4; i++)
    #pragma unroll
    for (int j = 0; j < 8; j++) acc[i][j] = (floatx4)0.f;

  const int r0  = tid >> 2;            // 0..31
  const int cc0 = (((tid & 3) ^ ((r0 >> 1) & 3)) * 8);   // XOR-swizzled k-offset
  const u16* Ag = A  + (size_t)m0 * K;
  const u16* Bg = Bt + (size_t)n0 * K;

  const int fswz = (l16 >> 1) & 3;
  const int aoff = (quad ^ fswz) * 8;

  // buffer layout (u16): buf i at i*8192 = [A 4096 | B 4096].
  // Staging: 8 gld_lds16/thread; gld j covers rows [j*32+wave*16, +16),
  // source row j*32+r0 (row>>1&3 swizzle term is j-invariant: j*32 ≡ 0 mod 4
  // after >>1). Dest = linear wave-uniform base + lane*16B (gld_lds rule).
#define STG(kk, bufo) do {                                                            \
    _Pragma("unroll")                                                                 \
    for (int j = 0; j < 4; j++)                                                       \
      gld_lds16(Ag + (size_t)(j * 32 + r0) * K + (kk) + cc0,                          \
                &smem[(bufo) + j * 1024 + wave * 512]);                               \
    _Pragma("unroll")                                                                 \
    for (int j = 0; j < 4; j++)                                                       \
      gld_lds16(Bg + (size_t)(j * 32 + r0) * K + (kk) + cc0,                          \
                &smem[(bufo) + 4096 + j * 1024 + wave * 512]);                        \
  } while (0)

  // prologue: stage tiles 0 and 1 (16 loads); vmcnt(8) drains tile 0's 8.
  STG(0, 0);
  STG(32, 8192);
  asm volatile("s_waitcnt vmcnt(8)" ::: "memory");
  __builtin_amdgcn_s_barrier();

  int bc = 0;        // compute-buffer offset (t   % 3)
  int bs = 16384;    // stage-buffer offset   (t+2 % 3)
  for (int k0 = 0; k0 < K; k0 += 32) {
    if (k0 + 64 < K) STG(k0 + 64, bs);
    const u16* As = &smem[bc];
    const u16* Bs = &smem[bc + 4096];
    short8 af[4], bf[8];
    #pragma unroll
    for (int mi = 0; mi < 4; mi++)
      af[mi] = *(const short8*)&As[(wm + mi*16 + l16) * 32 + aoff];
    #pragma unroll
    for (int ni = 0; ni < 8; ni++)
      bf[ni] = *(const short8*)&Bs[(ni*16 + l16) * 32 + aoff];
    #pragma unroll
    for (int mi = 0; mi < 4; mi++)
      #pragma unroll
      for (int ni = 0; ni < 8; ni++)
        acc[mi][ni] = __builtin_amdgcn_mfma_f32_16x16x32_bf16(
            af[mi], bf[ni], acc[mi][ni], 0, 0, 0);
    if (k0 + 64 < K) {
      asm volatile("s_waitcnt vmcnt(8)" ::: "memory");   // t+1 landed, t+2 in flight
    } else if (k0 + 32 < K) {
      asm volatile("s_waitcnt vmcnt(0)" ::: "memory");   // tail: drain last tile
    }
    __builtin_amdgcn_s_barrier();
    bc = (bc == 16384) ? 0 : bc + 8192;
    bs = (bs == 16384) ? 0 : bs + 8192;
  }
#undef STG

  if (MODE == 3) {
    const int mrow = m0 + wm + quad * 4;
    const int ncol = n0 + l16;
    #pragma unroll
    for (int ni = 0; ni < 8; ni++) {
      const int n = ncol + ni * 16;
      const float bv = bias[n];
      #pragma unroll
      for (int mi = 0; mi < 4; mi++)
        #pragma unroll
        for (int r = 0; r < 4; r++) {
          const size_t idx = (size_t)(mrow + mi * 16 + r) * N + n;
          ((float*)outp)[idx] = acc[mi][ni][r] + bv + bf2f(((const u16*)res)[idx]);
        }
    }
  } else {
    #pragma unroll
    for (int ni = 0; ni < 8; ni++) {
      const int col = ni * 16 + l16;
      const float bv = bias[n0 + col];
      #pragma unroll
      for (int mi = 0; mi < 4; mi++)
        #pragma unroll
        for (int r = 0; r < 4; r++) {
          float v = acc[mi][ni][r] + bv;
          if (MODE == 1) v = gelu_f(v);
          smem[(wm + mi * 16 + quad * 4 + r) * CSTR + col] = f2bf(v);
        }
    }
    __syncthreads();
    const int trow = tid >> 4;            // 0..7
    const int tcol = (tid & 15) * 8;      // u16 col
    #pragma unroll
    for (int it = 0; it < 16; it++) {
      const int row = it * 8 + trow;
      uint4 w = *(const uint4*)&smem[row * CSTR + tcol];
      const size_t gi = (size_t)(m0 + row) * N + n0 + tcol;
      if (MODE == 2) {
        const float* rp = (const float*)res + gi;
        float4 ra = *(const float4*)rp;
        float4 rb = *(const float4*)(rp + 4);
        u32 w0 = (u32)f2bf(bf2f_lo(w.x) + ra.x) | ((u32)f2bf(bf2f_hi(w.x) + ra.y) << 16);
        u32 w1 = (u32)f2bf(bf2f_lo(w.y) + ra.z) | ((u32)f2bf(bf2f_hi(w.y) + ra.w) << 16);
        u32 w2 = (u32)f2bf(bf2f_lo(w.z) + rb.x) | ((u32)f2bf(bf2f_hi(w.z) + rb.y) << 16);
        u32 w3 = (u32)f2bf(bf2f_lo(w.w) + rb.z) | ((u32)f2bf(bf2f_hi(w.w) + rb.w) << 16);
        *(uint4*)((u16*)outp + gi) = make_uint4(w0, w1, w2, w3);
      } else {
        *(uint4*)((u16*)outp + gi) = w;
      }
    }
  }
}

// ---------- MFMA windowed attention: one wave per (window, head) ----------
// (unchanged from the verified round-4/5 version)
__global__ __launch_bounds__(256, 3)
void attn_k(const u16* __restrict__ QKV, const float* __restrict__ relL,
            u16* __restrict__ O) {
  __shared__ __align__(16) u16 Vt[4][32][PSTR];    // V^T per wave
  __shared__ __align__(16) u16 Pl[4][49 * PSTR];   // P, then O bounce

  const int tid  = threadIdx.x;
  const int wave = tid >> 6;
  const int lane = tid & 63;
  const int quad = lane >> 4;
  const int l16  = lane & 15;

  const int win  = blockIdx.x >> 2;                // 0..1023
  const int head = ((blockIdx.x & 3) << 2) + wave; // 0..15
  const int b    = win >> 6;
  const int wh   = (win >> 3) & 7;
  const int ww   = win & 7;
  const int base_l = b * Ll + (wh * 7) * Ww + ww * 7;

  // ---- stage V^T into LDS (all 64 lanes; pad rows k>=49 zeroed) ----
  u32 vw[16];
  #pragma unroll
  for (int i = 0; i < 16; i++) vw[i] = 0;
  const int lc = lane < 49 ? lane : 48;
  const size_t grl = (size_t)base_l + (lc / 7) * 56 + (lc % 7);
  if (lane < 49) {
    const uint4* vp = (const uint4*)(QKV + grl * 1536 + 1024 + head * HDd);
    uint4 a0 = vp[0], a1 = vp[1], a2 = vp[2], a3 = vp[3];
    vw[0]=a0.x;  vw[1]=a0.y;  vw[2]=a0.z;  vw[3]=a0.w;
    vw[4]=a1.x;  vw[5]=a1.y;  vw[6]=a1.z;  vw[7]=a1.w;
    vw[8]=a2.x;  vw[9]=a2.y;  vw[10]=a2.z; vw[11]=a2.w;
    vw[12]=a3.x; vw[13]=a3.y; vw[14]=a3.z; vw[15]=a3.w;
  }
  {
    u16* vtb = &Vt[wave][0][lane];
    #pragma unroll
    for (int c = 0; c < 32; c++)
      vtb[c * PSTR] = (u16)(vw[c >> 1] >> ((c & 1) << 4));
  }

  // ---- Q/K fragments direct from global (row-clamped) ----
  size_t gr16[4];
  #pragma unroll
  for (int t = 0; t < 4; t++) {
    int r = t * 16 + l16; if (r > 48) r = 48;
    gr16[t] = (size_t)base_l + (r / 7) * 56 + (r % 7);
  }
  short8 qf[4], kf[4];
  #pragma unroll
  for (int t = 0; t < 4; t++) {
    qf[t] = *(const short8*)(QKV + gr16[t] * 1536 + head * HDd + quad * 8);
    kf[t] = *(const short8*)(QKV + gr16[t] * 1536 + 512 + head * HDd + quad * 8);
  }

  // ---- QK^T: 16 MFMA ----
  floatx4 acc[4][4];
  #pragma unroll
  for (int mi = 0; mi < 4; mi++)
    #pragma unroll
    for (int nj = 0; nj < 4; nj++) acc[mi][nj] = (floatx4)0.f;
  #pragma unroll
  for (int mi = 0; mi < 4; mi++)
    #pragma unroll
    for (int nj = 0; nj < 4; nj++)
      acc[mi][nj] = __builtin_amdgcn_mfma_f32_16x16x32_bf16(
          qf[mi], kf[nj], acc[mi][nj], 0, 0, 0);

  // ---- scale + rel bias (mask baked in) ----
  const float* rlb = relL + ((size_t)head << 12) + lane * 4;
  #pragma unroll
  for (int mi = 0; mi < 4; mi++)
    #pragma unroll
    for (int nj = 0; nj < 4; nj++) {
      float4 rl = *(const float4*)(rlb + ((mi * 4 + nj) << 8));
      acc[mi][nj][0] = fmaf(acc[mi][nj][0], SCALE, rl.x);
      acc[mi][nj][1] = fmaf(acc[mi][nj][1], SCALE, rl.y);
      acc[mi][nj][2] = fmaf(acc[mi][nj][2], SCALE, rl.z);
      acc[mi][nj][3] = fmaf(acc[mi][nj][3], SCALE, rl.w);
    }

  // ---- row softmax (rows live in 16-lane groups; xor 1,2,4,8) ----
  float sums[4][4];
  #pragma unroll
  for (int mi = 0; mi < 4; mi++)
    #pragma unroll
    for (int r = 0; r < 4; r++) {
      float mx = fmaxf(fmaxf(acc[mi][0][r], acc[mi][1][r]),
                       fmaxf(acc[mi][2][r], acc[mi][3][r]));
      #pragma unroll
      for (int off = 8; off >= 1; off >>= 1)
        mx = fmaxf(mx, __shfl_xor(mx, off));
      float sm = 0.f;
      #pragma unroll
      for (int nj = 0; nj < 4; nj++) {
        float e = __expf(acc[mi][nj][r] - mx);
        acc[mi][nj][r] = e;
        sm += e;
      }
      #pragma unroll
      for (int off = 8; off >= 1; off >>= 1)
        sm += __shfl_xor(sm, off);
      sums[mi][r] = sm;
    }

  // ---- P -> bf16 -> LDS (rows<49; row 48 only from mi=3,quad=0,r=0) ----
  u16* Pw = Pl[wave];
  {
    u16* pb = Pw + (quad * 4) * PSTR + l16;
    #pragma unroll
    for (int mi = 0; mi < 3; mi++)
      #pragma unroll
      for (int r = 0; r < 4; r++)
        #pragma unroll
        for (int nj = 0; nj < 4; nj++)
          pb[(mi * 16 + r) * PSTR + nj * 16] = f2bf(acc[mi][nj][r]);
    if (quad == 0) {
      #pragma unroll
      for (int nj = 0; nj < 4; nj++)
        pb[48 * PSTR + nj * 16] = f2bf(acc[3][nj][0]);
    }
  }
  asm volatile("s_waitcnt lgkmcnt(0)" ::: "memory");

  // ---- PV: 16 MFMA (A = P rows, B = V cols via Vt) ----
  floatx4 pv[4][2];
  #pragma unroll
  for (int mi = 0; mi < 4; mi++)
    #pragma unroll
    for (int nj = 0; nj < 2; nj++) pv[mi][nj] = (floatx4)0.f;
  #pragma unroll
  for (int ks = 0; ks < 2; ks++) {
    short8 pf[4], vf[2];
    #pragma unroll
    for (int mi = 0; mi < 4; mi++) {
      const int pr = (mi < 3) ? (mi * 16 + l16) : 48;
      pf[mi] = *(const short8*)&Pw[pr * PSTR + ks * 32 + quad * 8];
    }
    #pragma unroll
    for (int nj = 0; nj < 2; nj++)
      vf[nj] = *(const short8*)&Vt[wave][nj * 16 + l16][ks * 32 + quad * 8];
    #pragma unroll
    for (int mi = 0; mi < 4; mi++)
      #pragma unroll
      for (int nj = 0; nj < 2; nj++)
        pv[mi][nj] = __builtin_amdgcn_mfma_f32_16x16x32_bf16(
            pf[mi], vf[nj], pv[mi][nj], 0, 0, 0);
  }

  // ---- O = pv/sum -> LDS bounce (reuse P buffer) -> coalesced store ----
  asm volatile("s_waitcnt lgkmcnt(0)" ::: "memory");
  {
    u16* ob = Pw + (quad * 4) * PSTR + l16;
    #pragma unroll
    for (int mi = 0; mi < 3; mi++)
      #pragma unroll
      for (int r = 0; r < 4; r++) {
        const float inv = __builtin_amdgcn_rcpf(sums[mi][r]);
        ob[(mi * 16 + r) * PSTR +  0] = f2bf(pv[mi][0][r] * inv);
        ob[(mi * 16 + r) * PSTR + 16] = f2bf(pv[mi][1][r] * inv);
      }
    if (quad == 0) {
      const float inv = __builtin_amdgcn_rcpf(sums[3][0]);
      ob[48 * PSTR +  0] = f2bf(pv[3][0][0] * inv);
      ob[48 * PSTR + 16] = f2bf(pv[3][1][0] * inv);
    }
  }
  asm volatile("s_waitcnt lgkmcnt(0)" ::: "memory");
  if (lane < 49) {
    const uint4* orow = (const uint4*)&Pw[lane * PSTR];
    uint4* op = (uint4*)(O + grl * 512 + head * HDd);
    op[0] = orow[0]; op[1] = orow[1]; op[2] = orow[2]; op[3] = orow[3];
  }
}

// ---------- launch ----------
extern "C" void kernel_launch(void* const* d_in, const int* in_sizes, int n_in,
                              void* d_out, int out_size, void* d_ws, size_t ws_size,
                              hipStream_t stream) {
  (void)in_sizes; (void)n_in; (void)out_size; (void)ws_size;
  const float* x    = (const float*)d_in[0];
  const float* Wq   = (const float*)d_in[1];
  const float* bq   = (const float*)d_in[2];
  const float* Wk   = (const float*)d_in[3];
  const float* bk   = (const float*)d_in[4];
  const float* Wv   = (const float*)d_in[5];
  const float* bv   = (const float*)d_in[6];
  const float* Wp   = (const float*)d_in[7];
  const float* bp   = (const float*)d_in[8];
  const float* rel  = (const float*)d_in[9];
  const float* g1   = (const float*)d_in[10];
  const float* b1   = (const float*)d_in[11];
  const float* g2   = (const float*)d_in[12];
  const float* b2   = (const float*)d_in[13];
  const float* W1   = (const float*)d_in[14];
  const float* bfc1 = (const float*)d_in[15];
  const float* W2   = (const float*)d_in[16];
  const float* bfc2 = (const float*)d_in[17];
  float* out = (float*)d_out;

  // workspace layout (u16 units)
  u16* wQKV = (u16*)d_ws;                          // 1536*512
  u16* wWp  = wQKV + (size_t)1536*512;             // 512*512
  u16* wW1  = wWp  + (size_t)512*512;              // 2048*512
  u16* wW2  = wW1  + (size_t)2048*512;             // 512*2048
  float* bqkv = (float*)(wW2 + (size_t)512*2048);  // 1536 fp32
  float* relL = bqkv + 1536;                       // 65536 fp32 (256 KB)
  u16* hbuf = (u16*)(relL + 65536);                // M*512 (LN1 out; later LN2 out)
  u16* QKVb = hbuf + (size_t)Mm * Cc;              // M*1536 (later: MLP hidden part)
  u16* Obuf = QKVb + (size_t)Mm * 1536;            // M*512
  u16* x2bf = Obuf + (size_t)Mm * Cc;              // M*512 bf16 residual
  u16* hid  = QKVb;                                // M*2048 overlays QKVb+Obuf
  u16* h2   = hbuf;

  // fused prep: all weight transposes + bias concat + rel prep, ONE launch
  prep_k<<<12545, 256, 0, stream>>>(Wq, Wk, Wv, Wp, W1, W2, bq, bk, bv, rel,
                                    wQKV, wWp, wW1, wW2, bqkv, relL);

  // LN1
  ln_k<<<Mm/4, 256, 0, stream>>>(x, g1, b1, hbuf);

  // fused QKV projection: (M,1536), 392*12 blocks x 128 threads
  gemm_bt<0><<<392*12, 128, 0, stream>>>(hbuf, wQKV, bqkv, nullptr, QKVb,
                                         Mm, 1536, 512, 12);

  // attention (MFMA): 4096 blocks x 256 threads, 4 window-heads/block
  attn_k<<<4096, 256, 0, stream>>>(QKVb, relL, Obuf);

  // proj + residual(x fp32) -> x2 bf16
  gemm_bt<2><<<392*4, 128, 0, stream>>>(Obuf, wWp, bp, x, x2bf,
                                        Mm, 512, 512, 4);

  // LN2 (bf16 in)
  ln_bf_k<<<Mm/4, 256, 0, stream>>>(x2bf, g2, b2, h2);

  // MLP
  gemm_bt<1><<<392*16, 128, 0, stream>>>(h2, wW1, bfc1, nullptr, hid,
                                         Mm, 2048, 512, 16);
  gemm_bt<3><<<392*4, 128, 0, stream>>>(hid, wW2, bfc2, x2bf, out,
                                        Mm, 512, 2048, 4);
}

// Round 12
// 769.394 us; speedup vs baseline: 1.2012x; 1.2012x over previous
//
#include <hip/hip_runtime.h>

typedef unsigned short u16;
typedef unsigned int   u32;

using short8  = __attribute__((ext_vector_type(8))) short;
using floatx4 = __attribute__((ext_vector_type(4))) float;

// ---------- constants ----------
#define Bb   16
#define Hh   56
#define Ww   56
#define Cc   512
#define NHh  16
#define HDd  32
#define HIDh 2048
#define Ll   (Hh*Ww)          // 3136
#define Mm   (Bb*Ll)          // 50176
#define SCALE 0.17677669529663687f
#define CSTR 136              // GEMM C-tile LDS row stride (u16)
#define PSTR 72               // attn LDS row stride (u16): 144B = 16B-aligned

// ---------- helpers ----------
__device__ __forceinline__ u16 f2bf(float f) {
  union { float f; u32 u; } v; v.f = f;
  u32 r = (v.u + 0x7fffu + ((v.u >> 16) & 1u)) >> 16;
  return (u16)r;
}
__device__ __forceinline__ float bf2f(u16 u) {
  union { u32 u; float f; } v; v.u = ((u32)u) << 16; return v.f;
}
__device__ __forceinline__ float bf2f_lo(u32 u) {
  union { u32 u; float f; } v; v.u = u << 16; return v.f;
}
__device__ __forceinline__ float bf2f_hi(u32 u) {
  union { u32 u; float f; } v; v.u = u & 0xffff0000u; return v.f;
}
// gelu with A&S 7.1.26 erf (|err| < 1.5e-7): ~2x cheaper than libm erff.
__device__ __forceinline__ float gelu_f(float x) {
  const float z  = x * 0.70710678118654752f;
  const float az = fabsf(z);
  const float t  = __builtin_amdgcn_rcpf(fmaf(0.3275911f, az, 1.f));
  float p = fmaf(1.061405429f, t, -1.453152027f);
  p = fmaf(p, t, 1.421413741f);
  p = fmaf(p, t, -0.284496736f);
  p = fmaf(p, t, 0.254829592f);
  const float e = p * t * __expf(-z * z);     // 1 - erf(|z|)
  float erfz = 1.f - e;
  erfz = copysignf(erfz, z);
  return 0.5f * x * (1.f + erfz);
}
__device__ __forceinline__ void gld_lds16(const u16* g, u16* l) {
  __builtin_amdgcn_global_load_lds(
      (__attribute__((address_space(1))) void*)(void*)g,
      (__attribute__((address_space(3))) void*)(void*)l,
      16, 0, 0);
}

// ---------- fused prep: weight cvt+transpose (row-major Wt[n][k]) +
//            bias concat + rel-bias fragment prep — ONE launch ----------
// block ranges: [0,3072) wQKV | [3072,4096) wWp | [4096,8192) wW1 |
//               [8192,12288) wW2 | [12288,12544) relL | 12544 bcat
__global__ __launch_bounds__(256)
void prep_k(const float* __restrict__ Wq, const float* __restrict__ Wk,
            const float* __restrict__ Wv, const float* __restrict__ Wp,
            const float* __restrict__ W1, const float* __restrict__ W2,
            const float* __restrict__ bq, const float* __restrict__ bk,
            const float* __restrict__ bv, const float* __restrict__ rel,
            u16* __restrict__ wQKV, u16* __restrict__ wWp,
            u16* __restrict__ wW1, u16* __restrict__ wW2,
            float* __restrict__ bqkv, float* __restrict__ relL) {
  const int blk = blockIdx.x;
  if (blk < 3072) {            // wQKV: 3 matrices 512x512, Wt[n][k]=W[k][n]
    int idx = blk * 256 + threadIdx.x;     // 0..786431
    int m = idx >> 18;                     // which of Wq/Wk/Wv
    int r = idx & 262143;
    int n = r >> 9, k = r & 511;
    const float* W = (m == 0) ? Wq : (m == 1) ? Wk : Wv;
    wQKV[idx] = f2bf(W[(size_t)k * 512 + n]);
  } else if (blk < 4096) {     // wWp: 512x512
    int idx = (blk - 3072) * 256 + threadIdx.x;
    int n = idx >> 9, k = idx & 511;
    wWp[idx] = f2bf(Wp[(size_t)k * 512 + n]);
  } else if (blk < 8192) {     // wW1: N=2048, K=512
    int idx = (blk - 4096) * 256 + threadIdx.x;
    int n = idx >> 9, k = idx & 511;
    wW1[idx] = f2bf(W1[(size_t)k * 2048 + n]);
  } else if (blk < 12288) {    // wW2: N=512, K=2048
    int idx = (blk - 8192) * 256 + threadIdx.x;
    int n = idx >> 11, k = idx & 2047;
    wW2[idx] = f2bf(W2[(size_t)k * 512 + n]);
  } else if (blk < 12544) {    // relL: MFMA D-fragment layout, masks baked
    int idx  = (blk - 12288) * 256 + threadIdx.x;   // 0..65535
    int reg  = idx & 3;
    int lane = (idx >> 2) & 63;
    int frag = (idx >> 8) & 15;
    int h    = idx >> 12;
    int mi = frag >> 2, nj = frag & 3;
    int row = mi * 16 + (lane >> 4) * 4 + reg;
    int col = nj * 16 + (lane & 15);
    float v;
    if (col >= 49)      v = -1e30f;
    else if (row >= 49) v = 0.f;
    else                v = rel[((size_t)h * 49 + row) * 49 + col];
    relL[idx] = v;
  } else {                     // bcat: 1536 elems
    for (int i = threadIdx.x; i < 1536; i += 256) {
      float v = (i < 512) ? bq[i] : (i < 1024) ? bk[i - 512] : bv[i - 1024];
      bqkv[i] = v;
    }
  }
}

// ---------- layernorm fp32 in -> bf16 out, one wave per row ----------
__global__ __launch_bounds__(256)
void ln_k(const float* __restrict__ x, const float* __restrict__ g,
          const float* __restrict__ b, u16* __restrict__ out) {
  const int row  = blockIdx.x * 4 + (threadIdx.x >> 6);
  const int lane = threadIdx.x & 63;
  const float* xr = x + (size_t)row * Cc + lane * 8;
  float4 v0 = *(const float4*)xr;
  float4 v1 = *(const float4*)(xr + 4);
  float s  = v0.x+v0.y+v0.z+v0.w + v1.x+v1.y+v1.z+v1.w;
  float s2 = v0.x*v0.x+v0.y*v0.y+v0.z*v0.z+v0.w*v0.w
           + v1.x*v1.x+v1.y*v1.y+v1.z*v1.z+v1.w*v1.w;
  #pragma unroll
  for (int off = 32; off >= 1; off >>= 1) {
    s  += __shfl_xor(s,  off);
    s2 += __shfl_xor(s2, off);
  }
  float mu  = s  * (1.f/512.f);
  float var = s2 * (1.f/512.f) - mu*mu;
  float rs  = rsqrtf(var + 1e-5f);
  float4 ga = *(const float4*)(g + lane*8);
  float4 gb = *(const float4*)(g + lane*8 + 4);
  float4 ba = *(const float4*)(b + lane*8);
  float4 bb = *(const float4*)(b + lane*8 + 4);
  float o0 = (v0.x-mu)*rs*ga.x + ba.x;
  float o1 = (v0.y-mu)*rs*ga.y + ba.y;
  float o2 = (v0.z-mu)*rs*ga.z + ba.z;
  float o3 = (v0.w-mu)*rs*ga.w + ba.w;
  float o4 = (v1.x-mu)*rs*gb.x + bb.x;
  float o5 = (v1.y-mu)*rs*gb.y + bb.y;
  float o6 = (v1.z-mu)*rs*gb.z + bb.z;
  float o7 = (v1.w-mu)*rs*gb.w + bb.w;
  u32 w0 = (u32)f2bf(o0) | ((u32)f2bf(o1) << 16);
  u32 w1 = (u32)f2bf(o2) | ((u32)f2bf(o3) << 16);
  u32 w2 = (u32)f2bf(o4) | ((u32)f2bf(o5) << 16);
  u32 w3 = (u32)f2bf(o6) | ((u32)f2bf(o7) << 16);
  *(uint4*)(out + (size_t)row * Cc + lane * 8) = make_uint4(w0, w1, w2, w3);
}

// ---------- layernorm bf16 in -> bf16 out ----------
__global__ __launch_bounds__(256)
void ln_bf_k(const u16* __restrict__ x, const float* __restrict__ g,
             const float* __restrict__ b, u16* __restrict__ out) {
  const int row  = blockIdx.x * 4 + (threadIdx.x >> 6);
  const int lane = threadIdx.x & 63;
  uint4 xv = *(const uint4*)(x + (size_t)row * Cc + lane * 8);
  float v[8];
  v[0]=bf2f_lo(xv.x); v[1]=bf2f_hi(xv.x); v[2]=bf2f_lo(xv.y); v[3]=bf2f_hi(xv.y);
  v[4]=bf2f_lo(xv.z); v[5]=bf2f_hi(xv.z); v[6]=bf2f_lo(xv.w); v[7]=bf2f_hi(xv.w);
  float s = 0.f, s2 = 0.f;
  #pragma unroll
  for (int i = 0; i < 8; i++) { s += v[i]; s2 += v[i]*v[i]; }
  #pragma unroll
  for (int off = 32; off >= 1; off >>= 1) {
    s  += __shfl_xor(s,  off);
    s2 += __shfl_xor(s2, off);
  }
  float mu  = s  * (1.f/512.f);
  float var = s2 * (1.f/512.f) - mu*mu;
  float rs  = rsqrtf(var + 1e-5f);
  float4 ga = *(const float4*)(g + lane*8);
  float4 gb = *(const float4*)(g + lane*8 + 4);
  float4 ba = *(const float4*)(b + lane*8);
  float4 bb = *(const float4*)(b + lane*8 + 4);
  float o[8];
  o[0]=(v[0]-mu)*rs*ga.x+ba.x; o[1]=(v[1]-mu)*rs*ga.y+ba.y;
  o[2]=(v[2]-mu)*rs*ga.z+ba.z; o[3]=(v[3]-mu)*rs*ga.w+ba.w;
  o[4]=(v[4]-mu)*rs*gb.x+bb.x; o[5]=(v[5]-mu)*rs*gb.y+bb.y;
  o[6]=(v[6]-mu)*rs*gb.z+bb.z; o[7]=(v[7]-mu)*rs*gb.w+bb.w;
  u32 w0 = (u32)f2bf(o[0]) | ((u32)f2bf(o[1]) << 16);
  u32 w1 = (u32)f2bf(o[2]) | ((u32)f2bf(o[3]) << 16);
  u32 w2 = (u32)f2bf(o[4]) | ((u32)f2bf(o[5]) << 16);
  u32 w3 = (u32)f2bf(o[6]) | ((u32)f2bf(o[7]) << 16);
  *(uint4*)(out + (size_t)row * Cc + lane * 8) = make_uint4(w0, w1, w2, w3);
}

// ---------- GEMM: out[M,N] = A[M,K](bf16) @ Bt[N,K](bf16)^T + bias ----------
// 128x128 tile, BK=32, 256 threads (4 waves, 2x2), XCD-aware swizzle.
// TRIPLE-buffered LDS (3 x 16 KB) with depth-2 prefetch + counted vmcnt
// (verified best: MLP2 177us, MfmaUtil 25.3%): step t stages tile t+2 into
// buf[(t+2)%3], computes buf[t%3], ends with vmcnt(4) — never 0 mid-loop.
// One barrier per step. LDS 49152 B -> 3 blocks/CU (12 waves/CU).
// [Local-optimum note: r5 depth-2=marginal, r9 B-from-L2=-7%, r11 2-wave
//  =-29% (occupancy/VALU exposure + bank conflicts). The ~25% MfmaUtil is
//  the 4-wave barrier-lockstep balance point for these skinny-N shapes;
//  unilateral traffic/occupancy moves all lose. Do not re-litigate without
//  a new counter signal.]
// MODE 0: -> bf16   MODE 1: gelu -> bf16   MODE 2: +res(fp32) -> bf16
// MODE 3: +res(bf16) -> fp32 (direct stores)
template<int MODE>
__global__ __launch_bounds__(256, 3)
void gemm_bt(const u16* __restrict__ A, const u16* __restrict__ Bt,
             const float* __restrict__ bias, const void* __restrict__ res,
             void* __restrict__ outp, int M, int N, int K, int nbn) {
  (void)M;
  __shared__ __align__(16) u16 smem[24576];   // 49152 B; 3 bufs; aliases C-stage

  const int b   = blockIdx.x;
  const int xcd = b & 7;
  const int s   = b >> 3;
  const int mt  = (s / nbn) * 8 + xcd;
  const int nt  = s - (s / nbn) * nbn;
  const int m0  = mt * 128;
  const int n0  = nt * 128;

  const int tid  = threadIdx.x;
  const int lane = tid & 63;
  const int wave = tid >> 6;
  const int wm = (wave >> 1) * 64;
  const int wn = (wave & 1) * 64;
  const int quad = lane >> 4;
  const int l16  = lane & 15;

  floatx4 acc[4][4];
  #pragma unroll
  for (int i = 0; i < 4; i++)
    #pragma unroll
    for (int j = 0; j < 4; j++) acc[i][j] = (floatx4)0.f;

  const int r0  = tid >> 2;
  const int cc0 = (((tid & 3) ^ ((r0 >> 1) & 3)) * 8);   // XOR-swizzled k-offset
  const u16* Ag = A  + (size_t)m0 * K;
  const u16* Bg = Bt + (size_t)n0 * K;

  const int fswz = (l16 >> 1) & 3;
  const int aoff = (quad ^ fswz) * 8;

  // buffer layout (u16): buf i at i*8192 = [A 4096 | B 4096]
#define STG(kk, bufo) do {                                                        \
    gld_lds16(Ag + (size_t)r0        * K + (kk) + cc0, &smem[(bufo) + wave * 512]);        \
    gld_lds16(Ag + (size_t)(r0 + 64) * K + (kk) + cc0, &smem[(bufo) + 2048 + wave * 512]); \
    gld_lds16(Bg + (size_t)r0        * K + (kk) + cc0, &smem[(bufo) + 4096 + wave * 512]); \
    gld_lds16(Bg + (size_t)(r0 + 64) * K + (kk) + cc0, &smem[(bufo) + 6144 + wave * 512]); \
  } while (0)

  // prologue: stage tiles 0 and 1 (K >= 512 always => nT >= 16)
  STG(0, 0);
  STG(32, 8192);
  asm volatile("s_waitcnt vmcnt(4)" ::: "memory");   // tile 0 landed
  __builtin_amdgcn_s_barrier();

  int bc = 0;        // compute-buffer offset (t   % 3)
  int bs = 16384;    // stage-buffer offset   (t+2 % 3)
  for (int k0 = 0; k0 < K; k0 += 32) {
    if (k0 + 64 < K) STG(k0 + 64, bs);
    const u16* As = &smem[bc];
    const u16* Bs = &smem[bc + 4096];
    short8 af[4], bf[4];
    #pragma unroll
    for (int mi = 0; mi < 4; mi++)
      af[mi] = *(const short8*)&As[(wm + mi*16 + l16) * 32 + aoff];
    #pragma unroll
    for (int ni = 0; ni < 4; ni++)
      bf[ni] = *(const short8*)&Bs[(wn + ni*16 + l16) * 32 + aoff];
    #pragma unroll
    for (int mi = 0; mi < 4; mi++)
      #pragma unroll
      for (int ni = 0; ni < 4; ni++)
        acc[mi][ni] = __builtin_amdgcn_mfma_f32_16x16x32_bf16(
            af[mi], bf[ni], acc[mi][ni], 0, 0, 0);
    if (k0 + 64 < K) {
      asm volatile("s_waitcnt vmcnt(4)" ::: "memory");   // t+1 landed, t+2 in flight
    } else if (k0 + 32 < K) {
      asm volatile("s_waitcnt vmcnt(0)" ::: "memory");   // tail: drain last tile
    }
    __builtin_amdgcn_s_barrier();
    bc = (bc == 16384) ? 0 : bc + 8192;
    bs = (bs == 16384) ? 0 : bs + 8192;
  }
#undef STG

  if (MODE == 3) {
    const int mrow = m0 + wm + quad * 4;
    const int ncol = n0 + wn + l16;
    #pragma unroll
    for (int ni = 0; ni < 4; ni++) {
      const int n = ncol + ni * 16;
      const float bv = bias[n];
      #pragma unroll
      for (int mi = 0; mi < 4; mi++)
        #pragma unroll
        for (int r = 0; r < 4; r++) {
          const size_t idx = (size_t)(mrow + mi * 16 + r) * N + n;
          ((float*)outp)[idx] = acc[mi][ni][r] + bv + bf2f(((const u16*)res)[idx]);
        }
    }
  } else {
    #pragma unroll
    for (int ni = 0; ni < 4; ni++) {
      const int col = wn + ni * 16 + l16;
      const float bv = bias[n0 + col];
      #pragma unroll
      for (int mi = 0; mi < 4; mi++)
        #pragma unroll
        for (int r = 0; r < 4; r++) {
          float v = acc[mi][ni][r] + bv;
          if (MODE == 1) v = gelu_f(v);
          smem[(wm + mi * 16 + quad * 4 + r) * CSTR + col] = f2bf(v);
        }
    }
    __syncthreads();
    const int trow = tid >> 4;            // 0..15
    const int tcol = (tid & 15) * 8;      // u16 col
    #pragma unroll
    for (int it = 0; it < 8; it++) {
      const int row = it * 16 + trow;
      uint4 w = *(const uint4*)&smem[row * CSTR + tcol];
      const size_t gi = (size_t)(m0 + row) * N + n0 + tcol;
      if (MODE == 2) {
        const float* rp = (const float*)res + gi;
        float4 ra = *(const float4*)rp;
        float4 rb = *(const float4*)(rp + 4);
        u32 w0 = (u32)f2bf(bf2f_lo(w.x) + ra.x) | ((u32)f2bf(bf2f_hi(w.x) + ra.y) << 16);
        u32 w1 = (u32)f2bf(bf2f_lo(w.y) + ra.z) | ((u32)f2bf(bf2f_hi(w.y) + ra.w) << 16);
        u32 w2 = (u32)f2bf(bf2f_lo(w.z) + rb.x) | ((u32)f2bf(bf2f_hi(w.z) + rb.y) << 16);
        u32 w3 = (u32)f2bf(bf2f_lo(w.w) + rb.z) | ((u32)f2bf(bf2f_hi(w.w) + rb.w) << 16);
        *(uint4*)((u16*)outp + gi) = make_uint4(w0, w1, w2, w3);
      } else {
        *(uint4*)((u16*)outp + gi) = w;
      }
    }
  }
}

// ---------- MFMA windowed attention: one wave per (window, head) ----------
// (unchanged from the verified round-4/5 version)
__global__ __launch_bounds__(256, 3)
void attn_k(const u16* __restrict__ QKV, const float* __restrict__ relL,
            u16* __restrict__ O) {
  __shared__ __align__(16) u16 Vt[4][32][PSTR];    // V^T per wave
  __shared__ __align__(16) u16 Pl[4][49 * PSTR];   // P, then O bounce

  const int tid  = threadIdx.x;
  const int wave = tid >> 6;
  const int lane = tid & 63;
  const int quad = lane >> 4;
  const int l16  = lane & 15;

  const int win  = blockIdx.x >> 2;                // 0..1023
  const int head = ((blockIdx.x & 3) << 2) + wave; // 0..15
  const int b    = win >> 6;
  const int wh   = (win >> 3) & 7;
  const int ww   = win & 7;
  const int base_l = b * Ll + (wh * 7) * Ww + ww * 7;

  // ---- stage V^T into LDS (all 64 lanes; pad rows k>=49 zeroed) ----
  u32 vw[16];
  #pragma unroll
  for (int i = 0; i < 16; i++) vw[i] = 0;
  const int lc = lane < 49 ? lane : 48;
  const size_t grl = (size_t)base_l + (lc / 7) * 56 + (lc % 7);
  if (lane < 49) {
    const uint4* vp = (const uint4*)(QKV + grl * 1536 + 1024 + head * HDd);
    uint4 a0 = vp[0], a1 = vp[1], a2 = vp[2], a3 = vp[3];
    vw[0]=a0.x;  vw[1]=a0.y;  vw[2]=a0.z;  vw[3]=a0.w;
    vw[4]=a1.x;  vw[5]=a1.y;  vw[6]=a1.z;  vw[7]=a1.w;
    vw[8]=a2.x;  vw[9]=a2.y;  vw[10]=a2.z; vw[11]=a2.w;
    vw[12]=a3.x; vw[13]=a3.y; vw[14]=a3.z; vw[15]=a3.w;
  }
  {
    u16* vtb = &Vt[wave][0][lane];
    #pragma unroll
    for (int c = 0; c < 32; c++)
      vtb[c * PSTR] = (u16)(vw[c >> 1] >> ((c & 1) << 4));
  }

  // ---- Q/K fragments direct from global (row-clamped) ----
  size_t gr16[4];
  #pragma unroll
  for (int t = 0; t < 4; t++) {
    int r = t * 16 + l16; if (r > 48) r = 48;
    gr16[t] = (size_t)base_l + (r / 7) * 56 + (r % 7);
  }
  short8 qf[4], kf[4];
  #pragma unroll
  for (int t = 0; t < 4; t++) {
    qf[t] = *(const short8*)(QKV + gr16[t] * 1536 + head * HDd + quad * 8);
    kf[t] = *(const short8*)(QKV + gr16[t] * 1536 + 512 + head * HDd + quad * 8);
  }

  // ---- QK^T: 16 MFMA ----
  floatx4 acc[4][4];
  #pragma unroll
  for (int mi = 0; mi < 4; mi++)
    #pragma unroll
    for (int nj = 0; nj < 4; nj++) acc[mi][nj] = (floatx4)0.f;
  #pragma unroll
  for (int mi = 0; mi < 4; mi++)
    #pragma unroll
    for (int nj = 0; nj < 4; nj++)
      acc[mi][nj] = __builtin_amdgcn_mfma_f32_16x16x32_bf16(
          qf[mi], kf[nj], acc[mi][nj], 0, 0, 0);

  // ---- scale + rel bias (mask baked in) ----
  const float* rlb = relL + ((size_t)head << 12) + lane * 4;
  #pragma unroll
  for (int mi = 0; mi < 4; mi++)
    #pragma unroll
    for (int nj = 0; nj < 4; nj++) {
      float4 rl = *(const float4*)(rlb + ((mi * 4 + nj) << 8));
      acc[mi][nj][0] = fmaf(acc[mi][nj][0], SCALE, rl.x);
      acc[mi][nj][1] = fmaf(acc[mi][nj][1], SCALE, rl.y);
      acc[mi][nj][2] = fmaf(acc[mi][nj][2], SCALE, rl.z);
      acc[mi][nj][3] = fmaf(acc[mi][nj][3], SCALE, rl.w);
    }

  // ---- row softmax (rows live in 16-lane groups; xor 1,2,4,8) ----
  float sums[4][4];
  #pragma unroll
  for (int mi = 0; mi < 4; mi++)
    #pragma unroll
    for (int r = 0; r < 4; r++) {
      float mx = fmaxf(fmaxf(acc[mi][0][r], acc[mi][1][r]),
                       fmaxf(acc[mi][2][r], acc[mi][3][r]));
      #pragma unroll
      for (int off = 8; off >= 1; off >>= 1)
        mx = fmaxf(mx, __shfl_xor(mx, off));
      float sm = 0.f;
      #pragma unroll
      for (int nj = 0; nj < 4; nj++) {
        float e = __expf(acc[mi][nj][r] - mx);
        acc[mi][nj][r] = e;
        sm += e;
      }
      #pragma unroll
      for (int off = 8; off >= 1; off >>= 1)
        sm += __shfl_xor(sm, off);
      sums[mi][r] = sm;
    }

  // ---- P -> bf16 -> LDS (rows<49; row 48 only from mi=3,quad=0,r=0) ----
  u16* Pw = Pl[wave];
  {
    u16* pb = Pw + (quad * 4) * PSTR + l16;
    #pragma unroll
    for (int mi = 0; mi < 3; mi++)
      #pragma unroll
      for (int r = 0; r < 4; r++)
        #pragma unroll
        for (int nj = 0; nj < 4; nj++)
          pb[(mi * 16 + r) * PSTR + nj * 16] = f2bf(acc[mi][nj][r]);
    if (quad == 0) {
      #pragma unroll
      for (int nj = 0; nj < 4; nj++)
        pb[48 * PSTR + nj * 16] = f2bf(acc[3][nj][0]);
    }
  }
  asm volatile("s_waitcnt lgkmcnt(0)" ::: "memory");

  // ---- PV: 16 MFMA (A = P rows, B = V cols via Vt) ----
  floatx4 pv[4][2];
  #pragma unroll
  for (int mi = 0; mi < 4; mi++)
    #pragma unroll
    for (int nj = 0; nj < 2; nj++) pv[mi][nj] = (floatx4)0.f;
  #pragma unroll
  for (int ks = 0; ks < 2; ks++) {
    short8 pf[4], vf[2];
    #pragma unroll
    for (int mi = 0; mi < 4; mi++) {
      const int pr = (mi < 3) ? (mi * 16 + l16) : 48;
      pf[mi] = *(const short8*)&Pw[pr * PSTR + ks * 32 + quad * 8];
    }
    #pragma unroll
    for (int nj = 0; nj < 2; nj++)
      vf[nj] = *(const short8*)&Vt[wave][nj * 16 + l16][ks * 32 + quad * 8];
    #pragma unroll
    for (int mi = 0; mi < 4; mi++)
      #pragma unroll
      for (int nj = 0; nj < 2; nj++)
        pv[mi][nj] = __builtin_amdgcn_mfma_f32_16x16x32_bf16(
            pf[mi], vf[nj], pv[mi][nj], 0, 0, 0);
  }

  // ---- O = pv/sum -> LDS bounce (reuse P buffer) -> coalesced store ----
  asm volatile("s_waitcnt lgkmcnt(0)" ::: "memory");
  {
    u16* ob = Pw + (quad * 4) * PSTR + l16;
    #pragma unroll
    for (int mi = 0; mi < 3; mi++)
      #pragma unroll
      for (int r = 0; r < 4; r++) {
        const float inv = __builtin_amdgcn_rcpf(sums[mi][r]);
        ob[(mi * 16 + r) * PSTR +  0] = f2bf(pv[mi][0][r] * inv);
        ob[(mi * 16 + r) * PSTR + 16] = f2bf(pv[mi][1][r] * inv);
      }
    if (quad == 0) {
      const float inv = __builtin_amdgcn_rcpf(sums[3][0]);
      ob[48 * PSTR +  0] = f2bf(pv[3][0][0] * inv);
      ob[48 * PSTR + 16] = f2bf(pv[3][1][0] * inv);
    }
  }
  asm volatile("s_waitcnt lgkmcnt(0)" ::: "memory");
  if (lane < 49) {
    const uint4* orow = (const uint4*)&Pw[lane * PSTR];
    uint4* op = (uint4*)(O + grl * 512 + head * HDd);
    op[0] = orow[0]; op[1] = orow[1]; op[2] = orow[2]; op[3] = orow[3];
  }
}

// ---------- launch ----------
extern "C" void kernel_launch(void* const* d_in, const int* in_sizes, int n_in,
                              void* d_out, int out_size, void* d_ws, size_t ws_size,
                              hipStream_t stream) {
  (void)in_sizes; (void)n_in; (void)out_size; (void)ws_size;
  const float* x    = (const float*)d_in[0];
  const float* Wq   = (const float*)d_in[1];
  const float* bq   = (const float*)d_in[2];
  const float* Wk   = (const float*)d_in[3];
  const float* bk   = (const float*)d_in[4];
  const float* Wv   = (const float*)d_in[5];
  const float* bv   = (const float*)d_in[6];
  const float* Wp   = (const float*)d_in[7];
  const float* bp   = (const float*)d_in[8];
  const float* rel  = (const float*)d_in[9];
  const float* g1   = (const float*)d_in[10];
  const float* b1   = (const float*)d_in[11];
  const float* g2   = (const float*)d_in[12];
  const float* b2   = (const float*)d_in[13];
  const float* W1   = (const float*)d_in[14];
  const float* bfc1 = (const float*)d_in[15];
  const float* W2   = (const float*)d_in[16];
  const float* bfc2 = (const float*)d_in[17];
  float* out = (float*)d_out;

  // workspace layout (u16 units)
  u16* wQKV = (u16*)d_ws;                          // 1536*512
  u16* wWp  = wQKV + (size_t)1536*512;             // 512*512
  u16* wW1  = wWp  + (size_t)512*512;              // 2048*512
  u16* wW2  = wW1  + (size_t)2048*512;             // 512*2048
  float* bqkv = (float*)(wW2 + (size_t)512*2048);  // 1536 fp32
  float* relL = bqkv + 1536;                       // 65536 fp32 (256 KB)
  u16* hbuf = (u16*)(relL + 65536);                // M*512 (LN1 out; later LN2 out)
  u16* QKVb = hbuf + (size_t)Mm * Cc;              // M*1536 (later: MLP hidden part)
  u16* Obuf = QKVb + (size_t)Mm * 1536;            // M*512
  u16* x2bf = Obuf + (size_t)Mm * Cc;              // M*512 bf16 residual
  u16* hid  = QKVb;                                // M*2048 overlays QKVb+Obuf
  u16* h2   = hbuf;

  // fused prep: all weight transposes + bias concat + rel prep, ONE launch
  prep_k<<<12545, 256, 0, stream>>>(Wq, Wk, Wv, Wp, W1, W2, bq, bk, bv, rel,
                                    wQKV, wWp, wW1, wW2, bqkv, relL);

  // LN1
  ln_k<<<Mm/4, 256, 0, stream>>>(x, g1, b1, hbuf);

  // fused QKV projection: (M,1536), 392*12 blocks
  gemm_bt<0><<<392*12, 256, 0, stream>>>(hbuf, wQKV, bqkv, nullptr, QKVb,
                                         Mm, 1536, 512, 12);

  // attention (MFMA): 4096 blocks x 256 threads, 4 window-heads/block
  attn_k<<<4096, 256, 0, stream>>>(QKVb, relL, Obuf);

  // proj + residual(x fp32) -> x2 bf16
  gemm_bt<2><<<392*4, 256, 0, stream>>>(Obuf, wWp, bp, x, x2bf,
                                        Mm, 512, 512, 4);

  // LN2 (bf16 in)
  ln_bf_k<<<Mm/4, 256, 0, stream>>>(x2bf, g2, b2, h2);

  // MLP
  gemm_bt<1><<<392*16, 256, 0, stream>>>(h2, wW1, bfc1, nullptr, hid,
                                         Mm, 2048, 512, 16);
  gemm_bt<3><<<392*4, 256, 0, stream>>>(hid, wW2, bfc2, x2bf, out,
                                        Mm, 512, 2048, 4);
}